// Round 8
// baseline (308.793 us; speedup 1.0000x reference)
//
#include <hip/hip_runtime.h>
#include <float.h>
#include <math.h>

// NNConv net: 2x edge-conditioned conv (scalar edge attr) + 2 FC + log_softmax.
// W_e = a_e*U_s + V_s over <=26 breakpoint segments of the scalar edge attr.
// Edges bucketed by segment (chunk-aligned so a wave chunk is single-segment);
// per wave: U/V columns register-cached (lane = out channel), per-lane metadata
// gather + readlane broadcast, unrolled break-free chunk loop.
// R7 post-mortem: lane=node tail had grid=79 blocks (79/256 CUs used!) + 64KB
// LDS (2 blocks/CU) -> 3.5% occupancy, latency-bound. R7 fix: block=64 (one
// wave), grid=313, h2sh 16KB, fc1/fc2 in 16-wide output chunks (bounded live
// regs, no dynamic reg indexing), s_load_dwordx16 per fc1 i-step.

#define NCONST 25
#define CH1 32   // edges per wave chunk, conv1
#define CH2 16   // edges per wave chunk, conv2
#define PACK_MASK 0x1FFFF  // edge id < 2^17 (E = 100000)

typedef float vf16 __attribute__((ext_vector_type(16)));
typedef float vf32 __attribute__((ext_vector_type(32)));

__device__ __forceinline__ void atomicMaxFloat(float* addr, float val) {
    if (val >= 0.f) atomicMax((int*)addr, __float_as_int(val));
    else            atomicMin((unsigned int*)addr, __float_as_uint(val));
}
__device__ __forceinline__ float readlane_f(float v, int l) {
    return __int_as_float(__builtin_amdgcn_readlane(__float_as_int(v), l));
}
__device__ __forceinline__ float elu_fast(float x) {
    return x > 0.f ? x : (__expf(x) - 1.f);   // abs err ~1e-7, threshold 0.115
}

// Fill: agg regions with -FLT_MAX, order arrays with -1, hist with 0.
__global__ void fill_kernel(float* agg, int nAgg, int* ords, int nOrd, int* hist, int nH) {
    int i = blockIdx.x * blockDim.x + threadIdx.x;
    int stride = gridDim.x * blockDim.x;
    int total = nAgg + nOrd + nH;
    for (; i < total; i += stride) {
        if (i < nAgg) agg[i] = -FLT_MAX;
        else if (i < nAgg + nOrd) ords[i - nAgg] = -1;
        else hist[i - nAgg - nOrd] = 0;
    }
}

// Per edge: segment rank for both convs (j = #breakpoints < a), LDS-aggregated
// histograms, store packed (j1 | j2<<8).
__global__ void assign_hist_kernel(const float* __restrict__ ea,
                                   const float* __restrict__ w1a, const float* __restrict__ b1a,
                                   const float* __restrict__ w2a, const float* __restrict__ b2a,
                                   int E, int* __restrict__ segpack, int* __restrict__ hist) {
    __shared__ float t1[NCONST], t2[NCONST];
    __shared__ int lh[64];
    int tid = threadIdx.x;
    if (tid < NCONST) {
        float w = w1a[tid]; t1[tid] = (w != 0.f) ? (-b1a[tid] / w) : INFINITY;
        float v = w2a[tid]; t2[tid] = (v != 0.f) ? (-b2a[tid] / v) : INFINITY;
    }
    if (tid < 64) lh[tid] = 0;
    __syncthreads();
    int e = blockIdx.x * blockDim.x + tid;
    bool valid = e < E;
    if (valid) {
        float a = ea[e];
        int j1 = 0, j2 = 0;
        for (int k = 0; k < NCONST; ++k) { j1 += (t1[k] < a); j2 += (t2[k] < a); }
        segpack[e] = j1 | (j2 << 8);
        atomicAdd(&lh[j1], 1); atomicAdd(&lh[32 + j2], 1);
    }
    __syncthreads();
    if (tid < 64 && lh[tid]) atomicAdd(&hist[tid], lh[tid]);
}

// Parallel hist load through LDS, then two lanes do the 26-step chunk-aligned
// exclusive scan LDS-resident.
__global__ void scanpad_kernel(const int* __restrict__ hist, int* __restrict__ cur) {
    __shared__ int h[64];
    int tid = threadIdx.x;
    h[tid] = hist[tid];
    __syncthreads();
    if (tid == 0) {
        int off = 0;
        for (int j = 0; j < 26; ++j) { cur[j] = off; off += ((h[j] + CH1 - 1) / CH1) * CH1; }
    } else if (tid == 1) {
        int off = 0;
        for (int j = 0; j < 26; ++j) { cur[32 + j] = off; off += ((h[32 + j] + CH2 - 1) / CH2) * CH2; }
    }
}

// Block-aggregated scatter: LDS rank + one global atomicAdd per (block,bin).
__global__ void scatter_kernel(const int* __restrict__ segpack, int E, int* __restrict__ cur,
                               int* __restrict__ order1, int* __restrict__ order2) {
    __shared__ int lh[64], lb[64];
    int tid = threadIdx.x;
    if (tid < 64) lh[tid] = 0;
    __syncthreads();
    int e = blockIdx.x * blockDim.x + tid;
    bool valid = e < E;
    int j1 = 0, j2 = 0, r1 = 0, r2 = 0;
    if (valid) {
        int p = segpack[e]; j1 = p & 0xFF; j2 = p >> 8;
        r1 = atomicAdd(&lh[j1], 1); r2 = atomicAdd(&lh[32 + j2], 1);
    }
    __syncthreads();
    if (tid < 64 && lh[tid]) lb[tid] = atomicAdd(&cur[tid], lh[tid]);
    __syncthreads();
    if (valid) {
        order1[lb[j1] + r1] = (j1 << 17) | e;
        order2[lb[32 + j2] + r2] = (j2 << 17) | e;
    }
}

// U_s = sum_{k active} wa_k*wb_k ; V_s = sum_{k active} ba_k*wb_k + bb.
// Rank-based mask per block (LDS-resident, no sort): unit k active in segment j
// iff wa>0: j>r_k; wa<0: j<=r_k; wa==0: ba>0, with r_k = #{l: t_l < t_k}.
__global__ void build_uv_fused(const float* w1a, const float* b1a, const float* w1b, const float* b1b,
                               const float* w2a, const float* b2a, const float* w2b, const float* b2b,
                               float* U1, float* V1, float* U2, float* V2) {
    __shared__ float swa[NCONST], sba[NCONST], st[NCONST];
    __shared__ int sr[NCONST];
    __shared__ unsigned msk_sh;
    int seg = blockIdx.y;
    int bx = blockIdx.x;
    int conv = (bx < 2) ? 0 : 1;
    const float* wa = conv ? w2a : w1a;
    const float* ba = conv ? b2a : b1a;
    int tid = threadIdx.x;
    if (tid < NCONST) {
        float w = wa[tid], b = ba[tid];
        swa[tid] = w; sba[tid] = b;
        st[tid] = (w != 0.f) ? (-b / w) : INFINITY;
    }
    __syncthreads();
    if (tid < NCONST) {
        int rk = 0;
        for (int l = 0; l < NCONST; ++l) rk += (st[l] < st[tid]) ? 1 : 0;
        sr[tid] = rk;
    }
    __syncthreads();
    if (tid == 0) {
        unsigned m = 0;
        for (int k = 0; k < NCONST; ++k) {
            float w = swa[k];
            bool act = (w > 0.f) ? (seg > sr[k])
                     : (w < 0.f) ? (seg <= sr[k])
                                 : (sba[k] > 0.f);
            if (act) m |= (1u << k);
        }
        msk_sh = m;
    }
    __syncthreads();
    unsigned msk = msk_sh;
    if (conv == 0) {
        int idx = bx * 256 + tid;           // < 512
        float u = 0.f, v = 0.f;
        for (int k = 0; k < NCONST; ++k)
            if (msk & (1u << k)) { float w = w1b[k * 512 + idx]; u = fmaf(swa[k], w, u); v = fmaf(sba[k], w, v); }
        v += b1b[idx];
        U1[seg * 512 + idx] = u; V1[seg * 512 + idx] = v;
    } else {
        int idx = (bx - 2) * 256 + tid;     // < 2048
        float u = 0.f, v = 0.f;
        for (int k = 0; k < NCONST; ++k)
            if (msk & (1u << k)) { float w = w2b[k * 2048 + idx]; u = fmaf(swa[k], w, u); v = fmaf(sba[k], w, v); }
        v += b2b[idx];
        U2[seg * 2048 + idx] = u; V2[seg * 2048 + idx] = v;
    }
}

// conv1 edges: IC=16, OC=32, half-wave per edge (2 edges/iter). U/V in
// ext-vector registers (launch_bounds raises VGPR budget; no scratch demotion).
__global__ void __launch_bounds__(256, 4)
edge1_kernel(const float* __restrict__ xin, const int* __restrict__ src,
             const int* __restrict__ tgt, const float* __restrict__ ea,
             const int* __restrict__ order, int cap,
             const float* __restrict__ U, const float* __restrict__ V,
             float* __restrict__ agg) {
    int wid = (blockIdx.x * blockDim.x + threadIdx.x) >> 6;
    int lane = threadIdx.x & 63;
    int base = wid * CH1;
    if (base >= cap) return;
    int pk = order[base + (lane & (CH1 - 1))];
    int p0 = __builtin_amdgcn_readfirstlane(pk);
    if (p0 < 0) return;                        // whole-pad chunk past used region
    int seg = p0 >> 17;
    int ev = (pk < 0) ? 0 : (pk & PACK_MASK);
    int sv = src[ev], tv = tgt[ev];
    float av = ea[ev];
    int half = lane >> 5, c = lane & 31;
    vf16 Ur, Vr;
    {
        const float* Us = U + seg * 512 + c;
        const float* Vs = V + seg * 512 + c;
#pragma unroll
        for (int i = 0; i < 16; ++i) { Ur[i] = Us[i * 32]; Vr[i] = Vs[i * 32]; }
    }
#pragma unroll
    for (int t = 0; t < CH1; t += 2) {
        int pA = __builtin_amdgcn_readlane(pk, t);
        int pB = __builtin_amdgcn_readlane(pk, t + 1);
        int sA = __builtin_amdgcn_readlane(sv, t);
        int sB = __builtin_amdgcn_readlane(sv, t + 1);
        int tA = __builtin_amdgcn_readlane(tv, t);
        int tB = __builtin_amdgcn_readlane(tv, t + 1);
        float aA = readlane_f(av, t);
        float aB = readlane_f(av, t + 1);
        const float* xA = xin + sA * 16;
        const float* xB = xin + sB * 16;
        float ah = half ? aB : aA;
        int   th = half ? tB : tA;
        int   ph = half ? pB : pA;
        float acc = 0.f;
#pragma unroll
        for (int i = 0; i < 16; ++i) {
            float xi = half ? xB[i] : xA[i];
            acc = fmaf(xi, fmaf(ah, Ur[i], Vr[i]), acc);
        }
        if (ph >= 0) atomicMaxFloat(&agg[th * 32 + c], acc);
    }
}

// conv2 edges: IC=32, OC=64, lane = out channel, A/B edge pair per iteration.
__global__ void __launch_bounds__(256, 2)
edge2_kernel(const float* __restrict__ xin, const int* __restrict__ src,
             const int* __restrict__ tgt, const float* __restrict__ ea,
             const int* __restrict__ order, int cap,
             const float* __restrict__ U, const float* __restrict__ V,
             float* __restrict__ agg) {
    int wid = (blockIdx.x * blockDim.x + threadIdx.x) >> 6;
    int lane = threadIdx.x & 63;
    int base = wid * CH2;
    if (base >= cap) return;
    int pk = order[base + (lane & (CH2 - 1))];
    int p0 = __builtin_amdgcn_readfirstlane(pk);
    if (p0 < 0) return;
    int seg = p0 >> 17;
    int ev = (pk < 0) ? 0 : (pk & PACK_MASK);
    int sv = src[ev], tv = tgt[ev];
    float av = ea[ev];
    vf32 Ur, Vr;
    {
        const float* Us = U + seg * 2048 + lane;
        const float* Vs = V + seg * 2048 + lane;
#pragma unroll
        for (int i = 0; i < 32; ++i) { Ur[i] = Us[i * 64]; Vr[i] = Vs[i * 64]; }
    }
#pragma unroll
    for (int t = 0; t < CH2; t += 2) {
        int pA = __builtin_amdgcn_readlane(pk, t);
        int pB = __builtin_amdgcn_readlane(pk, t + 1);
        int sA = __builtin_amdgcn_readlane(sv, t);
        int sB = __builtin_amdgcn_readlane(sv, t + 1);
        int tA = __builtin_amdgcn_readlane(tv, t);
        int tB = __builtin_amdgcn_readlane(tv, t + 1);
        float aA = readlane_f(av, t);
        float aB = readlane_f(av, t + 1);
        const float* xA = xin + sA * 32;
        const float* xB = xin + sB * 32;
        float accA = 0.f, accB = 0.f;
#pragma unroll
        for (int i = 0; i < 32; ++i) {
            accA = fmaf(xA[i], fmaf(aA, Ur[i], Vr[i]), accA);
            accB = fmaf(xB[i], fmaf(aB, Ur[i], Vr[i]), accB);
        }
        if (pA >= 0) atomicMaxFloat(&agg[tA * 64 + lane], accA);
        if (pB >= 0) atomicMaxFloat(&agg[tB * 64 + lane], accB);
    }
}

// conv1 node update: out = elu( fixup(agg) + x @ wr1 + bias1 )
__global__ void node1_kernel(const float* __restrict__ xin, const float* __restrict__ agg,
                             const float* __restrict__ wroot, const float* __restrict__ bias,
                             float* __restrict__ out, int N) {
    int idx = blockIdx.x * blockDim.x + threadIdx.x;
    if (idx >= N * 32) return;
    int n = idx >> 5, c = idx & 31;
    float v = agg[idx];
    if (v == -FLT_MAX) v = 0.f;
    float acc = v + bias[c];
#pragma unroll
    for (int i = 0; i < 16; ++i) acc = fmaf(xin[n * 16 + i], wroot[i * 32 + c], acc);
    out[idx] = acc > 0.f ? acc : expm1f(acc);
}

// Fused tail, lane = node, ONE WAVE per block (grid 313 -> every CU busy).
// Weights are wave-uniform -> s_load (scalar cache), no weight staging.
// h2 goes through a 16KB conflict-free LDS transpose ([i][lane], same-wave
// readback, no barriers). fc1/fc2 in 16-wide output chunks to bound live VGPRs
// (acc16 + oacc10, never h3[64]); node2 fully unrolled (no dynamic reg index).
__global__ void __launch_bounds__(64, 4)
tail_kernel(const float* __restrict__ h1, const float* __restrict__ agg2,
            const float* __restrict__ wr2, const float* __restrict__ bias2,
            const float* __restrict__ fc1w, const float* __restrict__ fc1b,
            const float* __restrict__ fc2w, const float* __restrict__ fc2b,
            float* __restrict__ out, int N) {
    __shared__ float h2sh[64 * 64];           // [i][lane], 16 KB
    int lane = threadIdx.x;                   // 0..63
    int n = blockIdx.x * 64 + lane;
    bool valid = n < N;
    int nc = valid ? n : N - 1;

    // h1 row in registers (constant-indexed everywhere below)
    float h1r[32];
    {
        const float4* h1v = (const float4*)(h1 + (size_t)nc * 32);
#pragma unroll
        for (int q = 0; q < 8; ++q) {
            float4 t = h1v[q];
            h1r[q*4+0] = t.x; h1r[q*4+1] = t.y; h1r[q*4+2] = t.z; h1r[q*4+3] = t.w;
        }
    }

    // ---- node2 in 4 chunks of 16 outputs: h2 = elu(fixup(agg2)+h1r@wr2+b2) ----
    const float4* a2v = (const float4*)(agg2 + (size_t)nc * 64);
#pragma unroll
    for (int g = 0; g < 4; ++g) {
        float acc[16];
#pragma unroll
        for (int q = 0; q < 4; ++q) {
            float4 t = a2v[g * 4 + q];
            const float* bb = bias2 + g * 16 + q * 4;
            acc[q*4+0] = (t.x == -FLT_MAX ? 0.f : t.x) + bb[0];
            acc[q*4+1] = (t.y == -FLT_MAX ? 0.f : t.y) + bb[1];
            acc[q*4+2] = (t.z == -FLT_MAX ? 0.f : t.z) + bb[2];
            acc[q*4+3] = (t.w == -FLT_MAX ? 0.f : t.w) + bb[3];
        }
#pragma unroll
        for (int i = 0; i < 32; ++i) {         // unrolled: h1r[i] constant index
            const float* wrow = wr2 + i * 64 + g * 16;   // uniform -> s_load
#pragma unroll
            for (int o = 0; o < 16; ++o) acc[o] = fmaf(h1r[i], wrow[o], acc[o]);
        }
#pragma unroll
        for (int o = 0; o < 16; ++o)
            h2sh[(g * 16 + o) * 64 + lane] = elu_fast(acc[o]);   // conflict-free
    }

    // ---- fc1 (8 chunks of 16) + elu + fc2 partial accumulation ----
    float oacc[10];
#pragma unroll
    for (int c = 0; c < 10; ++c) oacc[c] = fc2b[c];
#pragma unroll
    for (int g = 0; g < 8; ++g) {
        float acc[16];
#pragma unroll
        for (int o = 0; o < 16; ++o) acc[o] = fc1b[g * 16 + o];
#pragma unroll 4
        for (int i = 0; i < 64; ++i) {         // hi via own LDS column
            float hi = h2sh[i * 64 + lane];
            const float* wrow = fc1w + i * 128 + g * 16;  // uniform -> s_load_dwordx16
#pragma unroll
            for (int o = 0; o < 16; ++o) acc[o] = fmaf(hi, wrow[o], acc[o]);
        }
#pragma unroll
        for (int o = 0; o < 16; ++o) {
            float v = elu_fast(acc[o]);
            const float* w2r = fc2w + (g * 16 + o) * 10;  // uniform -> s_load
#pragma unroll
            for (int c = 0; c < 10; ++c) oacc[c] = fmaf(v, w2r[c], oacc[c]);
        }
    }

    // ---- log_softmax, fully in-lane ----
    float mx = oacc[0];
#pragma unroll
    for (int c = 1; c < 10; ++c) mx = fmaxf(mx, oacc[c]);
    float s = 0.f;
#pragma unroll
    for (int c = 0; c < 10; ++c) s += __expf(oacc[c] - mx);
    float lse = mx + __logf(s);
    if (valid) {
#pragma unroll
        for (int c = 0; c < 10; ++c) out[(size_t)n * 10 + c] = oacc[c] - lse;
    }
}

extern "C" void kernel_launch(void* const* d_in, const int* in_sizes, int n_in,
                              void* d_out, int out_size, void* d_ws, size_t ws_size,
                              hipStream_t stream) {
    const float* x     = (const float*)d_in[0];
    const int*   eidx  = (const int*)d_in[1];
    const float* ea    = (const float*)d_in[2];
    const float* w1a   = (const float*)d_in[3];
    const float* b1a   = (const float*)d_in[4];
    const float* w1b   = (const float*)d_in[5];
    const float* b1b   = (const float*)d_in[6];
    const float* wr1   = (const float*)d_in[7];
    const float* bias1 = (const float*)d_in[8];
    const float* w2a   = (const float*)d_in[9];
    const float* b2a   = (const float*)d_in[10];
    const float* w2b   = (const float*)d_in[11];
    const float* b2b   = (const float*)d_in[12];
    const float* wr2   = (const float*)d_in[13];
    const float* bias2 = (const float*)d_in[14];
    const float* fc1w  = (const float*)d_in[15];
    const float* fc1b  = (const float*)d_in[16];
    const float* fc2w  = (const float*)d_in[17];
    const float* fc2b  = (const float*)d_in[18];

    const int N = in_sizes[0] / 16;   // 20000
    const int E = in_sizes[2];        // 100000
    const int* src = eidx;
    const int* tgt = eidx + E;

    const int cap1 = ((E + 26 * (CH1 - 1)) + CH1 - 1) / CH1 * CH1;
    const int cap2 = ((E + 26 * (CH2 - 1)) + CH2 - 1) / CH2 * CH2;

    float* ws = (float*)d_ws;
    size_t off = 0;
    int*      hist = (int*)(ws + off);      off += 64;
    int*      cur  = (int*)(ws + off);      off += 64;
    int*      segp = (int*)(ws + off);      off += E;
    int*      ord1 = (int*)(ws + off);      off += cap1;   // ord1/ord2 contiguous
    int*      ord2 = (int*)(ws + off);      off += cap2;
    float*    U1   = ws + off;              off += 26 * 512;
    float*    V1   = ws + off;              off += 26 * 512;
    float*    U2   = ws + off;              off += 26 * 2048;
    float*    V2   = ws + off;              off += 26 * 2048;
    float*    AGG1 = ws + off;              off += (size_t)N * 32;   // AGG1/AGG2 contiguous
    float*    AGG2 = ws + off;              off += (size_t)N * 64;
    float*    H1b  = ws + off;              off += (size_t)N * 32;

    // 1. init: agg=-FLT_MAX, order arrays=-1, hist=0
    fill_kernel<<<512, 256, 0, stream>>>(AGG1, N * 96, ord1, cap1 + cap2, hist, 64);
    // 2. per-edge segment ranks + histograms
    assign_hist_kernel<<<(E + 255) / 256, 256, 0, stream>>>(ea, w1a, b1a, w2a, b2a, E, segp, hist);
    // 3. chunk-aligned bucket offsets
    scanpad_kernel<<<1, 64, 0, stream>>>(hist, cur);
    // 4. scatter edges into segment-sorted order arrays
    scatter_kernel<<<(E + 255) / 256, 256, 0, stream>>>(segp, E, cur, ord1, ord2);
    // 5. per-segment U/V tables, both convs
    build_uv_fused<<<dim3(10, 26), 256, 0, stream>>>(w1a, b1a, w1b, b1b, w2a, b2a, w2b, b2b,
                                                     U1, V1, U2, V2);
    // 6. conv1
    {
        int waves = cap1 / CH1;
        edge1_kernel<<<(waves + 3) / 4, 256, 0, stream>>>(x, src, tgt, ea, ord1, cap1, U1, V1, AGG1);
    }
    node1_kernel<<<(N * 32 + 255) / 256, 256, 0, stream>>>(x, AGG1, wr1, bias1, H1b, N);
    // 7. conv2
    {
        int waves = cap2 / CH2;
        edge2_kernel<<<(waves + 3) / 4, 256, 0, stream>>>(H1b, src, tgt, ea, ord2, cap2, U2, V2, AGG2);
    }
    // 8. fused tail, lane = node, one wave per block (313 blocks)
    tail_kernel<<<(N + 63) / 64, 64, 0, stream>>>(H1b, AGG2, wr2, bias2, fc1w, fc1b, fc2w, fc2b,
                                                  (float*)d_out, N);
}

// Round 9
// 271.734 us; speedup vs baseline: 1.1364x; 1.1364x over previous
//
#include <hip/hip_runtime.h>
#include <float.h>
#include <math.h>

// NNConv net: 2x edge-conditioned conv (scalar edge attr) + 2 FC + log_softmax.
// W_e = a_e*U_s + V_s over <=26 breakpoint segments of the scalar edge attr.
// Edges bucketed by segment (chunk-aligned so a wave chunk is single-segment);
// per wave: U/V columns register-cached (lane = out channel), per-lane metadata
// gather + readlane broadcast, unrolled break-free chunk loop.
// R8 post-mortem: lane=node tail is STRUCTURALLY parallelism-capped (313 waves
// on a 256-CU chip) and s_load-latency-bound (VALUBusy 3.6%). R4-R8 fusion
// attempts (53/92/57/114/133us) never beat the unfused R1-R3 tail (~25-30us,
// never in top-5). REVERTED tail to simple elementwise kernels: node2
// thread-per-(n,c), fc1 thread-per-(n,c) (40000 waves, coalesced L1-hot
// weights), fc2 wave-per-node.

#define NCONST 25
#define CH1 32   // edges per wave chunk, conv1
#define CH2 16   // edges per wave chunk, conv2
#define PACK_MASK 0x1FFFF  // edge id < 2^17 (E = 100000)

typedef float vf16 __attribute__((ext_vector_type(16)));
typedef float vf32 __attribute__((ext_vector_type(32)));

__device__ __forceinline__ void atomicMaxFloat(float* addr, float val) {
    if (val >= 0.f) atomicMax((int*)addr, __float_as_int(val));
    else            atomicMin((unsigned int*)addr, __float_as_uint(val));
}
__device__ __forceinline__ float readlane_f(float v, int l) {
    return __int_as_float(__builtin_amdgcn_readlane(__float_as_int(v), l));
}

// Fill: agg regions with -FLT_MAX, order arrays with -1, hist with 0.
__global__ void fill_kernel(float* agg, int nAgg, int* ords, int nOrd, int* hist, int nH) {
    int i = blockIdx.x * blockDim.x + threadIdx.x;
    int stride = gridDim.x * blockDim.x;
    int total = nAgg + nOrd + nH;
    for (; i < total; i += stride) {
        if (i < nAgg) agg[i] = -FLT_MAX;
        else if (i < nAgg + nOrd) ords[i - nAgg] = -1;
        else hist[i - nAgg - nOrd] = 0;
    }
}

// Per edge: segment rank for both convs (j = #breakpoints < a), LDS-aggregated
// histograms, store packed (j1 | j2<<8).
__global__ void assign_hist_kernel(const float* __restrict__ ea,
                                   const float* __restrict__ w1a, const float* __restrict__ b1a,
                                   const float* __restrict__ w2a, const float* __restrict__ b2a,
                                   int E, int* __restrict__ segpack, int* __restrict__ hist) {
    __shared__ float t1[NCONST], t2[NCONST];
    __shared__ int lh[64];
    int tid = threadIdx.x;
    if (tid < NCONST) {
        float w = w1a[tid]; t1[tid] = (w != 0.f) ? (-b1a[tid] / w) : INFINITY;
        float v = w2a[tid]; t2[tid] = (v != 0.f) ? (-b2a[tid] / v) : INFINITY;
    }
    if (tid < 64) lh[tid] = 0;
    __syncthreads();
    int e = blockIdx.x * blockDim.x + tid;
    bool valid = e < E;
    if (valid) {
        float a = ea[e];
        int j1 = 0, j2 = 0;
        for (int k = 0; k < NCONST; ++k) { j1 += (t1[k] < a); j2 += (t2[k] < a); }
        segpack[e] = j1 | (j2 << 8);
        atomicAdd(&lh[j1], 1); atomicAdd(&lh[32 + j2], 1);
    }
    __syncthreads();
    if (tid < 64 && lh[tid]) atomicAdd(&hist[tid], lh[tid]);
}

// Parallel hist load through LDS, then two lanes do the 26-step chunk-aligned
// exclusive scan LDS-resident.
__global__ void scanpad_kernel(const int* __restrict__ hist, int* __restrict__ cur) {
    __shared__ int h[64];
    int tid = threadIdx.x;
    h[tid] = hist[tid];
    __syncthreads();
    if (tid == 0) {
        int off = 0;
        for (int j = 0; j < 26; ++j) { cur[j] = off; off += ((h[j] + CH1 - 1) / CH1) * CH1; }
    } else if (tid == 1) {
        int off = 0;
        for (int j = 0; j < 26; ++j) { cur[32 + j] = off; off += ((h[32 + j] + CH2 - 1) / CH2) * CH2; }
    }
}

// Block-aggregated scatter: LDS rank + one global atomicAdd per (block,bin).
__global__ void scatter_kernel(const int* __restrict__ segpack, int E, int* __restrict__ cur,
                               int* __restrict__ order1, int* __restrict__ order2) {
    __shared__ int lh[64], lb[64];
    int tid = threadIdx.x;
    if (tid < 64) lh[tid] = 0;
    __syncthreads();
    int e = blockIdx.x * blockDim.x + tid;
    bool valid = e < E;
    int j1 = 0, j2 = 0, r1 = 0, r2 = 0;
    if (valid) {
        int p = segpack[e]; j1 = p & 0xFF; j2 = p >> 8;
        r1 = atomicAdd(&lh[j1], 1); r2 = atomicAdd(&lh[32 + j2], 1);
    }
    __syncthreads();
    if (tid < 64 && lh[tid]) lb[tid] = atomicAdd(&cur[tid], lh[tid]);
    __syncthreads();
    if (valid) {
        order1[lb[j1] + r1] = (j1 << 17) | e;
        order2[lb[32 + j2] + r2] = (j2 << 17) | e;
    }
}

// U_s = sum_{k active} wa_k*wb_k ; V_s = sum_{k active} ba_k*wb_k + bb.
// Rank-based mask per block (LDS-resident, no sort): unit k active in segment j
// iff wa>0: j>r_k; wa<0: j<=r_k; wa==0: ba>0, with r_k = #{l: t_l < t_k}.
__global__ void build_uv_fused(const float* w1a, const float* b1a, const float* w1b, const float* b1b,
                               const float* w2a, const float* b2a, const float* w2b, const float* b2b,
                               float* U1, float* V1, float* U2, float* V2) {
    __shared__ float swa[NCONST], sba[NCONST], st[NCONST];
    __shared__ int sr[NCONST];
    __shared__ unsigned msk_sh;
    int seg = blockIdx.y;
    int bx = blockIdx.x;
    int conv = (bx < 2) ? 0 : 1;
    const float* wa = conv ? w2a : w1a;
    const float* ba = conv ? b2a : b1a;
    int tid = threadIdx.x;
    if (tid < NCONST) {
        float w = wa[tid], b = ba[tid];
        swa[tid] = w; sba[tid] = b;
        st[tid] = (w != 0.f) ? (-b / w) : INFINITY;
    }
    __syncthreads();
    if (tid < NCONST) {
        int rk = 0;
        for (int l = 0; l < NCONST; ++l) rk += (st[l] < st[tid]) ? 1 : 0;
        sr[tid] = rk;
    }
    __syncthreads();
    if (tid == 0) {
        unsigned m = 0;
        for (int k = 0; k < NCONST; ++k) {
            float w = swa[k];
            bool act = (w > 0.f) ? (seg > sr[k])
                     : (w < 0.f) ? (seg <= sr[k])
                                 : (sba[k] > 0.f);
            if (act) m |= (1u << k);
        }
        msk_sh = m;
    }
    __syncthreads();
    unsigned msk = msk_sh;
    if (conv == 0) {
        int idx = bx * 256 + tid;           // < 512
        float u = 0.f, v = 0.f;
        for (int k = 0; k < NCONST; ++k)
            if (msk & (1u << k)) { float w = w1b[k * 512 + idx]; u = fmaf(swa[k], w, u); v = fmaf(sba[k], w, v); }
        v += b1b[idx];
        U1[seg * 512 + idx] = u; V1[seg * 512 + idx] = v;
    } else {
        int idx = (bx - 2) * 256 + tid;     // < 2048
        float u = 0.f, v = 0.f;
        for (int k = 0; k < NCONST; ++k)
            if (msk & (1u << k)) { float w = w2b[k * 2048 + idx]; u = fmaf(swa[k], w, u); v = fmaf(sba[k], w, v); }
        v += b2b[idx];
        U2[seg * 2048 + idx] = u; V2[seg * 2048 + idx] = v;
    }
}

// conv1 edges: IC=16, OC=32, half-wave per edge (2 edges/iter). U/V in
// ext-vector registers (launch_bounds raises VGPR budget; no scratch demotion).
__global__ void __launch_bounds__(256, 4)
edge1_kernel(const float* __restrict__ xin, const int* __restrict__ src,
             const int* __restrict__ tgt, const float* __restrict__ ea,
             const int* __restrict__ order, int cap,
             const float* __restrict__ U, const float* __restrict__ V,
             float* __restrict__ agg) {
    int wid = (blockIdx.x * blockDim.x + threadIdx.x) >> 6;
    int lane = threadIdx.x & 63;
    int base = wid * CH1;
    if (base >= cap) return;
    int pk = order[base + (lane & (CH1 - 1))];
    int p0 = __builtin_amdgcn_readfirstlane(pk);
    if (p0 < 0) return;                        // whole-pad chunk past used region
    int seg = p0 >> 17;
    int ev = (pk < 0) ? 0 : (pk & PACK_MASK);
    int sv = src[ev], tv = tgt[ev];
    float av = ea[ev];
    int half = lane >> 5, c = lane & 31;
    vf16 Ur, Vr;
    {
        const float* Us = U + seg * 512 + c;
        const float* Vs = V + seg * 512 + c;
#pragma unroll
        for (int i = 0; i < 16; ++i) { Ur[i] = Us[i * 32]; Vr[i] = Vs[i * 32]; }
    }
#pragma unroll
    for (int t = 0; t < CH1; t += 2) {
        int pA = __builtin_amdgcn_readlane(pk, t);
        int pB = __builtin_amdgcn_readlane(pk, t + 1);
        int sA = __builtin_amdgcn_readlane(sv, t);
        int sB = __builtin_amdgcn_readlane(sv, t + 1);
        int tA = __builtin_amdgcn_readlane(tv, t);
        int tB = __builtin_amdgcn_readlane(tv, t + 1);
        float aA = readlane_f(av, t);
        float aB = readlane_f(av, t + 1);
        const float* xA = xin + sA * 16;
        const float* xB = xin + sB * 16;
        float ah = half ? aB : aA;
        int   th = half ? tB : tA;
        int   ph = half ? pB : pA;
        float acc = 0.f;
#pragma unroll
        for (int i = 0; i < 16; ++i) {
            float xi = half ? xB[i] : xA[i];
            acc = fmaf(xi, fmaf(ah, Ur[i], Vr[i]), acc);
        }
        if (ph >= 0) atomicMaxFloat(&agg[th * 32 + c], acc);
    }
}

// conv2 edges: IC=32, OC=64, lane = out channel, A/B edge pair per iteration.
__global__ void __launch_bounds__(256, 2)
edge2_kernel(const float* __restrict__ xin, const int* __restrict__ src,
             const int* __restrict__ tgt, const float* __restrict__ ea,
             const int* __restrict__ order, int cap,
             const float* __restrict__ U, const float* __restrict__ V,
             float* __restrict__ agg) {
    int wid = (blockIdx.x * blockDim.x + threadIdx.x) >> 6;
    int lane = threadIdx.x & 63;
    int base = wid * CH2;
    if (base >= cap) return;
    int pk = order[base + (lane & (CH2 - 1))];
    int p0 = __builtin_amdgcn_readfirstlane(pk);
    if (p0 < 0) return;
    int seg = p0 >> 17;
    int ev = (pk < 0) ? 0 : (pk & PACK_MASK);
    int sv = src[ev], tv = tgt[ev];
    float av = ea[ev];
    vf32 Ur, Vr;
    {
        const float* Us = U + seg * 2048 + lane;
        const float* Vs = V + seg * 2048 + lane;
#pragma unroll
        for (int i = 0; i < 32; ++i) { Ur[i] = Us[i * 64]; Vr[i] = Vs[i * 64]; }
    }
#pragma unroll
    for (int t = 0; t < CH2; t += 2) {
        int pA = __builtin_amdgcn_readlane(pk, t);
        int pB = __builtin_amdgcn_readlane(pk, t + 1);
        int sA = __builtin_amdgcn_readlane(sv, t);
        int sB = __builtin_amdgcn_readlane(sv, t + 1);
        int tA = __builtin_amdgcn_readlane(tv, t);
        int tB = __builtin_amdgcn_readlane(tv, t + 1);
        float aA = readlane_f(av, t);
        float aB = readlane_f(av, t + 1);
        const float* xA = xin + sA * 32;
        const float* xB = xin + sB * 32;
        float accA = 0.f, accB = 0.f;
#pragma unroll
        for (int i = 0; i < 32; ++i) {
            accA = fmaf(xA[i], fmaf(aA, Ur[i], Vr[i]), accA);
            accB = fmaf(xB[i], fmaf(aB, Ur[i], Vr[i]), accB);
        }
        if (pA >= 0) atomicMaxFloat(&agg[tA * 64 + lane], accA);
        if (pB >= 0) atomicMaxFloat(&agg[tB * 64 + lane], accB);
    }
}

// conv1 node update: out = elu( fixup(agg) + x @ wr1 + bias1 )
__global__ void node1_kernel(const float* __restrict__ xin, const float* __restrict__ agg,
                             const float* __restrict__ wroot, const float* __restrict__ bias,
                             float* __restrict__ out, int N) {
    int idx = blockIdx.x * blockDim.x + threadIdx.x;
    if (idx >= N * 32) return;
    int n = idx >> 5, c = idx & 31;
    float v = agg[idx];
    if (v == -FLT_MAX) v = 0.f;
    float acc = v + bias[c];
#pragma unroll
    for (int i = 0; i < 16; ++i) acc = fmaf(xin[n * 16 + i], wroot[i * 32 + c], acc);
    out[idx] = acc > 0.f ? acc : expm1f(acc);
}

// conv2 node update: one thread per (n,c), c in [0,64). Wave covers one node:
// h1 reads broadcast, weight reads coalesced + L1-hot.
__global__ void node2_kernel(const float* __restrict__ h1, const float* __restrict__ agg,
                             const float* __restrict__ wroot, const float* __restrict__ bias,
                             float* __restrict__ out, int N) {
    int idx = blockIdx.x * blockDim.x + threadIdx.x;
    if (idx >= N * 64) return;
    int n = idx >> 6, c = idx & 63;
    float v = agg[idx];
    if (v == -FLT_MAX) v = 0.f;
    float acc = v + bias[c];
#pragma unroll
    for (int i = 0; i < 32; ++i) acc = fmaf(h1[n * 32 + i], wroot[i * 64 + c], acc);
    out[idx] = acc > 0.f ? acc : expm1f(acc);
}

// fc1: one thread per (n,c), c in [0,128). 40000 waves, weights coalesced.
__global__ void fc1_kernel(const float* __restrict__ h2, const float* __restrict__ w,
                           const float* __restrict__ b, float* __restrict__ out, int N) {
    int idx = blockIdx.x * blockDim.x + threadIdx.x;
    if (idx >= N * 128) return;
    int n = idx >> 7, c = idx & 127;
    float acc = b[c];
#pragma unroll
    for (int i = 0; i < 64; ++i) acc = fmaf(h2[n * 64 + i], w[i * 128 + c], acc);
    out[idx] = acc > 0.f ? acc : expm1f(acc);
}

// fc2 + log_softmax: one wave per node, lanes 0..9 compute logits.
__global__ void fc2_kernel(const float* __restrict__ h3, const float* __restrict__ w,
                           const float* __restrict__ b, float* __restrict__ out, int N) {
    int n = blockIdx.x * (blockDim.x / 64) + threadIdx.x / 64;
    int o = threadIdx.x % 64;
    if (n >= N) return;
    float logit = -FLT_MAX;
    if (o < 10) {
        float acc = b[o];
#pragma unroll
        for (int i = 0; i < 128; ++i) acc = fmaf(h3[n * 128 + i], w[i * 10 + o], acc);
        logit = acc;
    }
    float mx = -FLT_MAX;
#pragma unroll
    for (int i = 0; i < 10; ++i) mx = fmaxf(mx, __shfl(logit, i, 64));
    float s = 0.f;
#pragma unroll
    for (int i = 0; i < 10; ++i) s += expf(__shfl(logit, i, 64) - mx);
    if (o < 10) out[n * 10 + o] = logit - mx - logf(s);
}

extern "C" void kernel_launch(void* const* d_in, const int* in_sizes, int n_in,
                              void* d_out, int out_size, void* d_ws, size_t ws_size,
                              hipStream_t stream) {
    const float* x     = (const float*)d_in[0];
    const int*   eidx  = (const int*)d_in[1];
    const float* ea    = (const float*)d_in[2];
    const float* w1a   = (const float*)d_in[3];
    const float* b1a   = (const float*)d_in[4];
    const float* w1b   = (const float*)d_in[5];
    const float* b1b   = (const float*)d_in[6];
    const float* wr1   = (const float*)d_in[7];
    const float* bias1 = (const float*)d_in[8];
    const float* w2a   = (const float*)d_in[9];
    const float* b2a   = (const float*)d_in[10];
    const float* w2b   = (const float*)d_in[11];
    const float* b2b   = (const float*)d_in[12];
    const float* wr2   = (const float*)d_in[13];
    const float* bias2 = (const float*)d_in[14];
    const float* fc1w  = (const float*)d_in[15];
    const float* fc1b  = (const float*)d_in[16];
    const float* fc2w  = (const float*)d_in[17];
    const float* fc2b  = (const float*)d_in[18];

    const int N = in_sizes[0] / 16;   // 20000
    const int E = in_sizes[2];        // 100000
    const int* src = eidx;
    const int* tgt = eidx + E;

    const int cap1 = ((E + 26 * (CH1 - 1)) + CH1 - 1) / CH1 * CH1;
    const int cap2 = ((E + 26 * (CH2 - 1)) + CH2 - 1) / CH2 * CH2;

    float* ws = (float*)d_ws;
    size_t off = 0;
    int*      hist = (int*)(ws + off);      off += 64;
    int*      cur  = (int*)(ws + off);      off += 64;
    int*      segp = (int*)(ws + off);      off += E;
    int*      ord1 = (int*)(ws + off);      off += cap1;   // ord1/ord2 contiguous
    int*      ord2 = (int*)(ws + off);      off += cap2;
    float*    U1   = ws + off;              off += 26 * 512;
    float*    V1   = ws + off;              off += 26 * 512;
    float*    U2   = ws + off;              off += 26 * 2048;
    float*    V2   = ws + off;              off += 26 * 2048;
    float*    AGG1 = ws + off;              off += (size_t)N * 32;   // AGG1/AGG2 contiguous
    float*    AGG2 = ws + off;              off += (size_t)N * 64;
    float*    H1b  = ws + off;              off += (size_t)N * 32;
    float*    H2b  = ws + off;              off += (size_t)N * 64;
    float*    H3b  = ws + off;              off += (size_t)N * 128;

    // 1. init: agg=-FLT_MAX, order arrays=-1, hist=0
    fill_kernel<<<512, 256, 0, stream>>>(AGG1, N * 96, ord1, cap1 + cap2, hist, 64);
    // 2. per-edge segment ranks + histograms
    assign_hist_kernel<<<(E + 255) / 256, 256, 0, stream>>>(ea, w1a, b1a, w2a, b2a, E, segp, hist);
    // 3. chunk-aligned bucket offsets
    scanpad_kernel<<<1, 64, 0, stream>>>(hist, cur);
    // 4. scatter edges into segment-sorted order arrays
    scatter_kernel<<<(E + 255) / 256, 256, 0, stream>>>(segp, E, cur, ord1, ord2);
    // 5. per-segment U/V tables, both convs
    build_uv_fused<<<dim3(10, 26), 256, 0, stream>>>(w1a, b1a, w1b, b1b, w2a, b2a, w2b, b2b,
                                                     U1, V1, U2, V2);
    // 6. conv1
    {
        int waves = cap1 / CH1;
        edge1_kernel<<<(waves + 3) / 4, 256, 0, stream>>>(x, src, tgt, ea, ord1, cap1, U1, V1, AGG1);
    }
    node1_kernel<<<(N * 32 + 255) / 256, 256, 0, stream>>>(x, AGG1, wr1, bias1, H1b, N);
    // 7. conv2
    {
        int waves = cap2 / CH2;
        edge2_kernel<<<(waves + 3) / 4, 256, 0, stream>>>(H1b, src, tgt, ea, ord2, cap2, U2, V2, AGG2);
    }
    node2_kernel<<<(N * 64 + 255) / 256, 256, 0, stream>>>(H1b, AGG2, wr2, bias2, H2b, N);
    // 8. trailing FCs + log_softmax (simple, proven shapes)
    fc1_kernel<<<(N * 128 + 255) / 256, 256, 0, stream>>>(H2b, fc1w, fc1b, H3b, N);
    fc2_kernel<<<(N + 3) / 4, 256, 0, stream>>>(H3b, fc2w, fc2b, (float*)d_out, N);
}